// Round 5
// baseline (202.683 us; speedup 1.0000x reference)
//
#include <hip/hip_runtime.h>
#include <cmath>

#define IH 128
#define IW 128
#define NB 8

typedef __attribute__((ext_vector_type(8))) short bf16x8;
typedef __attribute__((ext_vector_type(4))) float f32x4;
typedef __attribute__((ext_vector_type(2))) float f32x2;

union U4B8 { uint4 u; bf16x8 h; };

// ws layout (float slots) — offm slot retained but unused after fusion:
//   offm  : [NB][27][IH][IW] f32      = 3538944
//   xT    : [NB][IH][IW][64] bf16     = 4194304 float slots (8388608 u16)
//   wt_dc : [9][64][64] bf16 (k,o,c)  = 18432 float slots
//   wt_om : [9][32][64] bf16 (k,o,c)  = 9216  float slots
#define OFFM_OFF 0
#define XT_OFF   3538944
#define WTDC_OFF (3538944 + 4194304)
#define WTOM_OFF (3538944 + 4194304 + 18432)

// fp32 -> bf16 bits, round-to-nearest-even
__device__ __forceinline__ unsigned short f32_to_bf16(float f) {
    unsigned int u = __float_as_uint(f);
    u += 0x7fffu + ((u >> 16) & 1u);
    return (unsigned short)(u >> 16);
}

// ---------------------------------------------------------------------------
// Kernel 0: weights -> bf16, layout [k][o][c]
// ---------------------------------------------------------------------------
__global__ void transpose_weights(const float* __restrict__ w_dc,
                                  const float* __restrict__ w_om,
                                  unsigned short* __restrict__ wt_dc16,
                                  unsigned short* __restrict__ wt_om16) {
    int idx = blockIdx.x * blockDim.x + threadIdx.x;
    if (idx < 9 * 64 * 64) {
        int k = idx >> 12;
        int o = (idx >> 6) & 63;
        int c = idx & 63;
        wt_dc16[idx] = f32_to_bf16(w_dc[(o * 64 + c) * 9 + k]);
    }
    if (idx < 9 * 32 * 64) {
        int k = idx >> 11;
        int o = (idx >> 6) & 31;
        int c = idx & 63;
        wt_om16[idx] = (o < 27) ? f32_to_bf16(w_om[(o * 64 + c) * 9 + k])
                                : (unsigned short)0;
    }
}

// ---------------------------------------------------------------------------
// Kernel 0b: x NCHW fp32 -> NHWC bf16 (xT[b][y][x][c])
// ---------------------------------------------------------------------------
__global__ __launch_bounds__(256) void transpose_x(
        const float* __restrict__ x, unsigned short* __restrict__ xT) {
    __shared__ float t[64 * 65];
    const int tid = threadIdx.x;
    const int blk = blockIdx.x;
    const int b = blk >> 8;
    const int rem = blk & 255;
    const int h = rem >> 1;
    const int w0 = (rem & 1) << 6;

    for (int i = tid; i < 4096; i += 256) {
        const int c = i >> 6;
        const int w = i & 63;
        t[w * 65 + c] = x[(((size_t)(b * 64 + c)) << 14) + (h << 7) + w0 + w];
    }
    __syncthreads();
    const int c2 = (tid & 31) * 2;
    ushort2* dst = (ushort2*)(xT + (((size_t)b << 20)) + ((size_t)((h << 7) + w0)) * 64 + c2);
#pragma unroll
    for (int p = 0; p < 8; ++p) {
        const int w = (tid >> 5) + p * 8;
        ushort2 u;
        u.x = f32_to_bf16(t[w * 65 + c2]);
        u.y = f32_to_bf16(t[w * 65 + c2 + 1]);
        dst[(size_t)w * 32] = u;
    }
}

// ---------------------------------------------------------------------------
// gather issue phase (deform): compute corner weights (msk premultiplied) and
// ISSUE the 8 corner loads into registers. Consumed one tap later.
// offs is an LDS pointer, stride 65 floats per channel.
// ---------------------------------------------------------------------------
__device__ __forceinline__ void issue_gather(
        const unsigned short* __restrict__ xb, const float* offs,
        int k, int lpx, int h, int w0, int quad, uint4* g, float* cw) {
    const float offy = offs[(k << 1) * 65 + lpx];
    const float offx = offs[((k << 1) + 1) * 65 + lpx];
    const float msk  = offs[(18 + k) * 65 + lpx];
    const int kh = k / 3;
    const int kw = k - kh * 3;
    const float py  = (float)(h + kh - 1) + offy;
    const float pxf = (float)(w0 + lpx + kw - 1) + offx;
    const float y0f = floorf(py);
    const float x0f = floorf(pxf);
    const float fy = py - y0f;
    const float fx = pxf - x0f;
    const float wy0 = 1.0f - fy, wx0 = 1.0f - fx;
    const float vy0 = (y0f >= 0.0f && y0f <= 127.0f) ? 1.0f : 0.0f;
    const float vy1 = (y0f >= -1.0f && y0f <= 126.0f) ? 1.0f : 0.0f;
    const float vx0 = (x0f >= 0.0f && x0f <= 127.0f) ? 1.0f : 0.0f;
    const float vx1 = (x0f >= -1.0f && x0f <= 126.0f) ? 1.0f : 0.0f;
    cw[0] = wy0 * wx0 * vy0 * vx0 * msk;
    cw[1] = wy0 * fx  * vy0 * vx1 * msk;
    cw[2] = fy  * wx0 * vy1 * vx0 * msk;
    cw[3] = fy  * fx  * vy1 * vx1 * msk;
    const int y0i = min(max((int)y0f, 0), 127);
    const int y1i = min(max((int)y0f + 1, 0), 127);
    const int x0i = min(max((int)x0f, 0), 127);
    const int x1i = min(max((int)x0f + 1, 0), 127);
    const int cofs = quad << 3;
    const unsigned short* p00 = xb + ((((size_t)((y0i << 7) + x0i)) << 6) + cofs);
    const unsigned short* p01 = xb + ((((size_t)((y0i << 7) + x1i)) << 6) + cofs);
    const unsigned short* p10 = xb + ((((size_t)((y1i << 7) + x0i)) << 6) + cofs);
    const unsigned short* p11 = xb + ((((size_t)((y1i << 7) + x1i)) << 6) + cofs);
    g[0] = *(const uint4*)p00;  g[1] = *(const uint4*)(p00 + 32);
    g[2] = *(const uint4*)p01;  g[3] = *(const uint4*)(p01 + 32);
    g[4] = *(const uint4*)p10;  g[5] = *(const uint4*)(p10 + 32);
    g[6] = *(const uint4*)p11;  g[7] = *(const uint4*)(p11 + 32);
}

// ---------------------------------------------------------------------------
// consume phase: combine 8 corner vectors with 4 (msk-premul) weights via
// packed-f32 FMA, pack to bf16 A-fragments via hw cvt_pk.
// ---------------------------------------------------------------------------
__device__ __forceinline__ void pack_frags(const uint4* g, const float* cw,
                                           U4B8& a0, U4B8& a1) {
    f32x2 v2[8];
#pragma unroll
    for (int i = 0; i < 8; ++i) v2[i] = (f32x2){0.f, 0.f};
#pragma unroll
    for (int c = 0; c < 4; ++c) {
        f32x2 w2;
        w2.x = cw[c];
        w2.y = cw[c];
        const uint4 ga = g[2 * c];
        const uint4 gb = g[2 * c + 1];
        const unsigned int u[8] = {ga.x, ga.y, ga.z, ga.w, gb.x, gb.y, gb.z, gb.w};
#pragma unroll
        for (int i = 0; i < 8; ++i) {
            f32x2 x2;
            x2.x = __uint_as_float(u[i] << 16);
            x2.y = __uint_as_float(u[i] & 0xffff0000u);
            asm("v_pk_fma_f32 %0, %1, %2, %0" : "+v"(v2[i]) : "v"(x2), "v"(w2));
        }
    }
    unsigned int pk[8];
#pragma unroll
    for (int i = 0; i < 8; ++i)
        asm("v_cvt_pk_bf16_f32 %0, %1, %2"
            : "=v"(pk[i]) : "v"(v2[i].x), "v"(v2[i].y));
    a0.u = make_uint4(pk[0], pk[1], pk[2], pk[3]);
    a1.u = make_uint4(pk[4], pk[5], pk[6], pk[7]);
}

// ---------------------------------------------------------------------------
// FUSED kernel: offset/mask conv (phase 1) + deformable conv (phase 2).
// Block = 64 px, 4 waves. Phase 1 is a pure register pipeline — A and B
// fragments both from global (L1/L2-hot), software-pipelined one tap ahead,
// NO LDS, NO barriers; result (27 ch/px) written to LDS offs[27][65].
// This deletes the conv_om kernel, its 28.5 KB window staging, its 9
// barriers, and the 28 MB offm global round-trip.
// Phase 2 = R4 deform: gather pipeline + LDS weight dbuf + lgkm-only barrier.
// ---------------------------------------------------------------------------
__global__ __launch_bounds__(256) void om_deform_fused(
        const unsigned short* __restrict__ xT,
        const float* __restrict__ b_om,
        const unsigned short* __restrict__ wt_om16,  // [9][32][64]
        const float* __restrict__ b_dc,
        const unsigned short* __restrict__ wt_dc16,  // [9][64][64]
        float* __restrict__ out) {
    __shared__ __align__(16) float offs[27 * 65];            // [ch][px] pad-65
    __shared__ __align__(16) unsigned short wks[2][64 * 72]; // [buf][o][72]

    const int tid = threadIdx.x;
    const int bid = blockIdx.x;
    const int swz = ((bid & 7) << 8) + (bid >> 3);   // XCD-contiguous
    const int b = swz >> 8;
    const int rem = swz & 255;
    const int h = rem >> 1;
    const int w0 = (rem & 1) << 6;
    const int wid = tid >> 6;
    const int lane = tid & 63;
    const int ln15 = lane & 15;
    const int quad = lane >> 4;
    const int lpx = (wid << 4) + ln15;   // local pixel this lane owns

    const unsigned short* xb = xT + ((size_t)b << 20);

    // ======================= phase 1: offset/mask conv ======================
    f32x4 oacc[2] = {{0.f, 0.f, 0.f, 0.f}, {0.f, 0.f, 0.f, 0.f}};
    uint4 pa[2][2];
    int   pav[2];
    uint4 pb[2][4];

#define ISSUE_A(K, S)                                                         \
    {                                                                         \
        const int kh_ = (K) / 3, kw_ = (K) - kh_ * 3;                         \
        const int y_ = h + kh_ - 1;                                           \
        const int xg_ = w0 + lpx + kw_ - 1;                                   \
        pav[S] = (y_ >= 0 && y_ < IH && xg_ >= 0 && xg_ < IW);                \
        const int yc_ = min(max(y_, 0), IH - 1);                              \
        const int xc_ = min(max(xg_, 0), IW - 1);                             \
        const unsigned short* p_ =                                            \
            xb + ((((size_t)((yc_ << 7) + xc_)) << 6) + (quad << 3));         \
        pa[S][0] = *(const uint4*)p_;                                         \
        pa[S][1] = *(const uint4*)(p_ + 32);                                  \
    }
#define ISSUE_B(K, S)                                                         \
    {                                                                         \
        const unsigned short* wg_ = wt_om16 + ((K) << 11) + (quad << 3);      \
        const unsigned short* q0_ = wg_ + (ln15 << 6);                        \
        const unsigned short* q1_ = wg_ + ((16 + ln15) << 6);                 \
        pb[S][0] = *(const uint4*)q0_;                                        \
        pb[S][1] = *(const uint4*)(q0_ + 32);                                 \
        pb[S][2] = *(const uint4*)q1_;                                        \
        pb[S][3] = *(const uint4*)(q1_ + 32);                                 \
    }

    ISSUE_B(0, 0)
    ISSUE_A(0, 0)
#pragma unroll
    for (int k = 0; k < 9; ++k) {
        const int cur = k & 1;
        const int nxt = cur ^ 1;
        if (k < 8) {            // pipeline: issue tap k+1 before consuming k
            ISSUE_B(k + 1, nxt)
            ISSUE_A(k + 1, nxt)
        }
        const uint4 z = make_uint4(0u, 0u, 0u, 0u);
        U4B8 a0, a1, b00, b01, b10, b11;
        a0.u = pav[cur] ? pa[cur][0] : z;   // border zero (select at consume,
        a1.u = pav[cur] ? pa[cur][1] : z;   //  after the natural vmcnt wait)
        b00.u = pb[cur][0];
        b01.u = pb[cur][1];
        b10.u = pb[cur][2];
        b11.u = pb[cur][3];
        oacc[0] = __builtin_amdgcn_mfma_f32_16x16x32_bf16(a0.h, b00.h, oacc[0], 0, 0, 0);
        oacc[0] = __builtin_amdgcn_mfma_f32_16x16x32_bf16(a1.h, b01.h, oacc[0], 0, 0, 0);
        oacc[1] = __builtin_amdgcn_mfma_f32_16x16x32_bf16(a0.h, b10.h, oacc[1], 0, 0, 0);
        oacc[1] = __builtin_amdgcn_mfma_f32_16x16x32_bf16(a1.h, b11.h, oacc[1], 0, 0, 0);
    }
#undef ISSUE_A
#undef ISSUE_B

    // stage wt_dc k=0 into wks[0] (2 x uint4 per thread)
    const int so0 = tid >> 3, sp = tid & 7;
    const int so1 = so0 + 32;
    {
        const uint4 wv0 = *(const uint4*)(wt_dc16 + (so0 << 6) + (sp << 3));
        const uint4 wv1 = *(const uint4*)(wt_dc16 + (so1 << 6) + (sp << 3));
        *(uint4*)&wks[0][so0 * 72 + sp * 8] = wv0;
        *(uint4*)&wks[0][so1 * 72 + sp * 8] = wv1;
    }

    // epilogue phase 1: bias (+2*sigmoid for mask ch) -> offs[ch][px] in LDS
    // C/D layout: col(o)=lane&15, row(px)=quad*4+reg
    const int px0 = (wid << 4) + (quad << 2);
#pragma unroll
    for (int ot = 0; ot < 2; ++ot) {
        const int o = (ot << 4) + ln15;
        if (o < 27) {
            const float bias = b_om[o];
            float r[4];
            r[0] = oacc[ot][0] + bias;
            r[1] = oacc[ot][1] + bias;
            r[2] = oacc[ot][2] + bias;
            r[3] = oacc[ot][3] + bias;
            if (o >= 18) {
#pragma unroll
                for (int j = 0; j < 4; ++j)
                    r[j] = 2.0f / (1.0f + __expf(-r[j]));
            }
#pragma unroll
            for (int j = 0; j < 4; ++j)
                offs[o * 65 + px0 + j] = r[j];
        }
    }
    __syncthreads();

    // ========================= phase 2: deform conv =========================
    f32x4 acc[4];
#pragma unroll
    for (int i = 0; i < 4; ++i) acc[i] = (f32x4){0.f, 0.f, 0.f, 0.f};

    uint4 g[2][8];
    float cw[2][4];
    issue_gather(xb, offs, 0, lpx, h, w0, quad, g[0], cw[0]);

#pragma unroll
    for (int k = 0; k < 9; ++k) {
        const int cur = k & 1;
        const int nxt = cur ^ 1;
        if (k < 8) {
            // 1) weight loads for k+1 (oldest in this iter's vmem FIFO)
            const uint4 wv0 = *(const uint4*)(wt_dc16 + ((k + 1) << 12) + (so0 << 6) + (sp << 3));
            const uint4 wv1 = *(const uint4*)(wt_dc16 + ((k + 1) << 12) + (so1 << 6) + (sp << 3));
            // 2) issue next-tap gather loads (newest — stay in flight)
            issue_gather(xb, offs, k + 1, lpx, h, w0, quad, g[nxt], cw[nxt]);
            // 3) ds_write W: waits vmcnt(8) -> drains W + gather(k) only
            *(uint4*)&wks[nxt][so0 * 72 + sp * 8] = wv0;
            *(uint4*)&wks[nxt][so1 * 72 + sp * 8] = wv1;
        }
        // 4) pack tap k from last iteration's registers
        U4B8 a0, a1;
        pack_frags(g[cur], cw[cur], a0, a1);
        // 5) MFMA from LDS weight broadcast
        const unsigned short* wb = wks[cur];
#pragma unroll
        for (int ot = 0; ot < 4; ++ot) {
            U4B8 b0, b1;
            const unsigned short* base = &wb[((ot << 4) + ln15) * 72 + (quad << 3)];
            b0.u = *(const uint4*)base;
            b1.u = *(const uint4*)(base + 32);
            acc[ot] = __builtin_amdgcn_mfma_f32_16x16x32_bf16(a0.h, b0.h, acc[ot], 0, 0, 0);
            acc[ot] = __builtin_amdgcn_mfma_f32_16x16x32_bf16(a1.h, b1.h, acc[ot], 0, 0, 0);
        }
        // 6) dbuf barrier: LDS-only wait — gather(k+1) loads stay in flight
        if (k < 8) {
            asm volatile("s_waitcnt lgkmcnt(0)" ::: "memory");
            __builtin_amdgcn_s_barrier();
            __builtin_amdgcn_sched_barrier(0);
        }
    }

    // epilogue: col(o)=lane&15, row(px)=quad*4+reg
#pragma unroll
    for (int ot = 0; ot < 4; ++ot) {
        const int o = (ot << 4) + ln15;
        const float bias = b_dc[o];
        float4 r;
        r.x = acc[ot][0] + bias;
        r.y = acc[ot][1] + bias;
        r.z = acc[ot][2] + bias;
        r.w = acc[ot][3] + bias;
        *(float4*)&out[(((size_t)(b * 64 + o)) << 14) + (h << 7) + w0 + (wid << 4) + (quad << 2)] = r;
    }
}

extern "C" void kernel_launch(void* const* d_in, const int* in_sizes, int n_in,
                              void* d_out, int out_size, void* d_ws, size_t ws_size,
                              hipStream_t stream) {
    const float* x    = (const float*)d_in[0];
    const float* w_om = (const float*)d_in[1];
    const float* b_om = (const float*)d_in[2];
    const float* w_dc = (const float*)d_in[3];
    const float* b_dc = (const float*)d_in[4];
    float* out = (float*)d_out;
    float* ws  = (float*)d_ws;

    unsigned short* xT      = (unsigned short*)(ws + XT_OFF);
    unsigned short* wt_dc16 = (unsigned short*)(ws + WTDC_OFF);
    unsigned short* wt_om16 = (unsigned short*)(ws + WTOM_OFF);

    // 64-px blocks: NB*IH*(IW/64) = 2048 blocks
    const int n_blocks = NB * IH * (IW / 64);

    transpose_weights<<<144, 256, 0, stream>>>(w_dc, w_om, wt_dc16, wt_om16);
    transpose_x<<<NB * IH * 2, 256, 0, stream>>>(x, xT);
    om_deform_fused<<<n_blocks, 256, 0, stream>>>(xT, b_om, wt_om16, b_dc, wt_dc16, out);
}